// Round 3
// baseline (173.181 us; speedup 1.0000x reference)
//
#include <hip/hip_runtime.h>
#include <hip/hip_cooperative_groups.h>
#include <math.h>

namespace cg = cooperative_groups;

#define NPTS 16384
#define NB   32
#define NA   4
#define NC   256
#define KNN  32
#define NROW 128   // NB*NA

// ws layout (floats): lf 128*256 | qkv 128*768 | res_lin 128*256 | prob_lin 128*9
#define OFF_QKV     32768
#define OFF_RESLIN  131072
#define OFF_PROBLIN 163840

__global__ __launch_bounds__(256) void fused_kernel(
    const float* __restrict__ a_points, const float* __restrict__ sa_x,
    const float* __restrict__ sa_xyz,
    const float* __restrict__ g_W, const float* __restrict__ g_gamma, const float* __restrict__ g_beta,
    const float* __restrict__ qkv_W,
    const float* __restrict__ pos_W, const float* __restrict__ pos_b,
    const float* __restrict__ pos_gamma, const float* __restrict__ pos_beta,
    const float* __restrict__ res_W, const float* __restrict__ res_b,
    const float* __restrict__ res_gamma, const float* __restrict__ res_beta,
    const float* __restrict__ prob_W, const float* __restrict__ prob_gamma, const float* __restrict__ prob_beta,
    float* ws, float* out)
{
  cg::grid_group grid = cg::this_grid();
  const int t   = threadIdx.x;
  const int blk = blockIdx.x;

  __shared__ float s_wv[4];
  __shared__ int   s_wi[4];
  __shared__ int   s_win;
  __shared__ int   s_top[KNN];
  __shared__ float lf_s[NC];
  __shared__ float apts[NROW * 3];
  __shared__ float av_s[NA][NC];
  __shared__ float feat_s[NA][2 * NC];
  __shared__ float pmn[9], prs[9];

  float* lf      = ws;
  float* qkv     = ws + OFF_QKV;
  float* res_lin = ws + OFF_RESLIN;
  float* prob_ln = ws + OFF_PROBLIN;

  // ================= Phase 1 (all 128 blocks): knn + maxpool + row-qkv =================
  {
    const int b = blk >> 2;
    const float ax = a_points[blk*3 + 0];
    const float ay = a_points[blk*3 + 1];
    const float az = a_points[blk*3 + 2];
    const float* __restrict__ xyz = sa_xyz + (size_t)b * NPTS * 3;

    float d[64];
#pragma unroll
    for (int j = 0; j < 64; ++j) {
      const int n = t + 256*j;
      const float dx = xyz[n*3+0] - ax;
      const float dy = xyz[n*3+1] - ay;
      const float dz = xyz[n*3+2] - az;
      d[j] = dx*dx + dy*dy + dz*dz;
    }
    float mv = d[0]; int mj = 0;
#pragma unroll
    for (int j = 1; j < 64; ++j) { if (d[j] < mv) { mv = d[j]; mj = j; } }
    int mi = t + 256*mj;

    const int lane = t & 63, w = t >> 6;
    for (int r = 0; r < KNN; ++r) {
      float v = mv; int i = mi;
#pragma unroll
      for (int off = 1; off < 64; off <<= 1) {
        const float ov = __shfl_xor(v, off);
        const int   oi = __shfl_xor(i, off);
        if (ov < v || (ov == v && oi < i)) { v = ov; i = oi; }
      }
      if (lane == 0) { s_wv[w] = v; s_wi[w] = i; }
      __syncthreads();
      if (t == 0) {
        float bv = s_wv[0]; int bi = s_wi[0];
#pragma unroll
        for (int w2 = 1; w2 < 4; ++w2)
          if (s_wv[w2] < bv || (s_wv[w2] == bv && s_wi[w2] < bi)) { bv = s_wv[w2]; bi = s_wi[w2]; }
        s_top[r] = bi; s_win = bi;
      }
      __syncthreads();
      const int wi = s_win;
      if ((wi & 255) == t) {
        const int kj = wi >> 8;
#pragma unroll
        for (int j = 0; j < 64; ++j) if (j == kj) d[j] = 3.0e38f;
        mv = d[0]; mj = 0;
#pragma unroll
        for (int j = 1; j < 64; ++j) { if (d[j] < mv) { mv = d[j]; mj = j; } }
        mi = t + 256*mj;
      }
    }
    __syncthreads();

    // gather + maxpool (thread t = channel t)
    const float* __restrict__ xb = sa_x + (size_t)b * NPTS * NC;
    float acc = -3.0e38f;
    for (int r = 0; r < KNN; ++r) {
      const int n = s_top[r];
      acc = fmaxf(acc, xb[(size_t)n * NC + t]);
    }
    lf_s[t] = acc;
    lf[(size_t)blk * NC + t] = acc;
    __syncthreads();

    // row-qkv GEMM: thread t owns outputs t, t+256, t+512 for row `blk`
    const float* __restrict__ w0p = qkv_W + (size_t)t * NC;
    const float* __restrict__ w1p = qkv_W + (size_t)(t + 256) * NC;
    const float* __restrict__ w2p = qkv_W + (size_t)(t + 512) * NC;
    float a0 = 0.f, a1 = 0.f, a2 = 0.f;
    for (int c = 0; c < NC; c += 4) {
      const float4 l4 = *(const float4*)&lf_s[c];
      const float4 w40 = *(const float4*)(w0p + c);
      const float4 w41 = *(const float4*)(w1p + c);
      const float4 w42 = *(const float4*)(w2p + c);
      a0 = fmaf(l4.x,w40.x,a0); a0 = fmaf(l4.y,w40.y,a0); a0 = fmaf(l4.z,w40.z,a0); a0 = fmaf(l4.w,w40.w,a0);
      a1 = fmaf(l4.x,w41.x,a1); a1 = fmaf(l4.y,w41.y,a1); a1 = fmaf(l4.z,w41.z,a1); a1 = fmaf(l4.w,w41.w,a1);
      a2 = fmaf(l4.x,w42.x,a2); a2 = fmaf(l4.y,w42.y,a2); a2 = fmaf(l4.z,w42.z,a2); a2 = fmaf(l4.w,w42.w,a2);
    }
    qkv[(size_t)blk*768 +       t] = a0;
    qkv[(size_t)blk*768 + 256 + t] = a1;
    qkv[(size_t)blk*768 + 512 + t] = a2;
  }
  grid.sync();

  // ================= Phase 2 (blocks 0..31): pos-BN + attention + res GEMM =================
  if (blk < NB) {
    const int b = blk;
    for (int i = t; i < NROW*3; i += 256) apts[i] = a_points[i];   // FIXED: full 384-element load
    __syncthreads();
    const int c = t;
    const float pw0 = pos_W[c*3+0], pw1 = pos_W[c*3+1], pw2 = pos_W[c*3+2];
    const float pbb = pos_b[c];
    float psum = 0.f, pss = 0.f;
    float posv[NA];
#pragma unroll
    for (int a = 0; a < NA; ++a) posv[a] = 0.f;
    for (int b2 = 0; b2 < NB; ++b2) {
      float gx=0.f, gy=0.f, gz=0.f;
#pragma unroll
      for (int a = 0; a < NA; ++a) {
        gx += apts[(b2*NA+a)*3+0];
        gy += apts[(b2*NA+a)*3+1];
        gz += apts[(b2*NA+a)*3+2];
      }
      gx *= 0.25f; gy *= 0.25f; gz *= 0.25f;
#pragma unroll
      for (int a = 0; a < NA; ++a) {
        const float v = (apts[(b2*NA+a)*3+0]-gx)*pw0
                      + (apts[(b2*NA+a)*3+1]-gy)*pw1
                      + (apts[(b2*NA+a)*3+2]-gz)*pw2 + pbb;
        psum += v; pss += v*v;
        if (b2 == b) posv[a] = v;
      }
    }
    const float pmean = psum * (1.0f/NROW);
    const float pvar  = pss * (1.0f/NROW) - pmean*pmean;
    const float prstd = 1.0f / sqrtf(pvar + 1e-5f);
    const float pga = pos_gamma[c], pbe = pos_beta[c];

    float q[NA], k[NA], vv[NA];
#pragma unroll
    for (int a = 0; a < NA; ++a) {
      const int row = b*NA + a;
      const float p = pga * (posv[a] - pmean) * prstd + pbe;
      q[a]  = qkv[(size_t)row*768 +       c] + p;
      k[a]  = qkv[(size_t)row*768 + 256 + c] + p;
      vv[a] = qkv[(size_t)row*768 + 512 + c] + p;
    }
    // attention: wave = head (c = head*64 + lane)
    float s[NA][NA];
#pragma unroll
    for (int m = 0; m < NA; ++m) {
#pragma unroll
      for (int n = 0; n < NA; ++n) {
        float p = q[m]*k[n];
#pragma unroll
        for (int off = 1; off < 64; off <<= 1) p += __shfl_xor(p, off);
        s[m][n] = p * 0.125f;   // 1/sqrt(64)
      }
    }
#pragma unroll
    for (int m = 0; m < NA; ++m) {
      const float mx = fmaxf(fmaxf(s[m][0], s[m][1]), fmaxf(s[m][2], s[m][3]));
      const float e0 = expf(s[m][0]-mx), e1 = expf(s[m][1]-mx);
      const float e2 = expf(s[m][2]-mx), e3 = expf(s[m][3]-mx);
      const float inv = 1.0f / (e0+e1+e2+e3);
      av_s[m][c] = (e0*vv[0] + e1*vv[1] + e2*vv[2] + e3*vv[3]) * inv;
    }
    __syncthreads();

    // res GEMM: thread c owns output channel c for the 4 rows of this batch
    const float* __restrict__ wrow = res_W + (size_t)c * NC;
    float r0=0.f, r1=0.f, r2=0.f, r3=0.f;
    for (int cc = 0; cc < NC; cc += 4) {
      const float4 w4 = *(const float4*)(wrow + cc);
      const float4 v0 = *(const float4*)&av_s[0][cc];
      const float4 v1 = *(const float4*)&av_s[1][cc];
      const float4 v2 = *(const float4*)&av_s[2][cc];
      const float4 v3 = *(const float4*)&av_s[3][cc];
      r0 = fmaf(v0.x,w4.x,r0); r0 = fmaf(v0.y,w4.y,r0); r0 = fmaf(v0.z,w4.z,r0); r0 = fmaf(v0.w,w4.w,r0);
      r1 = fmaf(v1.x,w4.x,r1); r1 = fmaf(v1.y,w4.y,r1); r1 = fmaf(v1.z,w4.z,r1); r1 = fmaf(v1.w,w4.w,r1);
      r2 = fmaf(v2.x,w4.x,r2); r2 = fmaf(v2.y,w4.y,r2); r2 = fmaf(v2.z,w4.z,r2); r2 = fmaf(v2.w,w4.w,r2);
      r3 = fmaf(v3.x,w4.x,r3); r3 = fmaf(v3.y,w4.y,r3); r3 = fmaf(v3.z,w4.z,r3); r3 = fmaf(v3.w,w4.w,r3);
    }
    const float bias = res_b[c];
    res_lin[(size_t)(b*NA+0)*NC + c] = r0 + bias;
    res_lin[(size_t)(b*NA+1)*NC + c] = r1 + bias;
    res_lin[(size_t)(b*NA+2)*NC + c] = r2 + bias;
    res_lin[(size_t)(b*NA+3)*NC + c] = r3 + bias;
  }
  grid.sync();

  // ================= Phase 3 (blocks 0..31): res-BN + add, g-BN + max, prob GEMM =================
  if (blk < NB) {
    const int b = blk, c = t;
    // res stats over all 128 rows (coalesced column scan)
    float rsum = 0.f, rss = 0.f;
    for (int row = 0; row < NROW; ++row) {
      const float v = res_lin[(size_t)row*NC + c];
      rsum += v; rss += v*v;
    }
    const float rmean = rsum * (1.0f/NROW);
    const float rvar  = rss * (1.0f/NROW) - rmean*rmean;
    const float rrstd = 1.0f / sqrtf(rvar + 1e-5f);
    const float rg = res_gamma[c], rb = res_beta[c];

    // g stats recomputed from a_points (apts persists in LDS from phase 2)
    const float gw0 = g_W[c*3+0], gw1 = g_W[c*3+1], gw2 = g_W[c*3+2];
    float gsum = 0.f, gss = 0.f;
    for (int row = 0; row < NROW; ++row) {
      const float v = apts[row*3+0]*gw0 + apts[row*3+1]*gw1 + apts[row*3+2]*gw2;
      gsum += v; gss += v*v;
    }
    const float gmean = gsum * (1.0f/NROW);
    const float gvar  = gss * (1.0f/NROW) - gmean*gmean;
    const float grstd = 1.0f / sqrtf(gvar + 1e-5f);
    const float gg = g_gamma[c], gb = g_beta[c];

    float gm = -3.0e38f;
#pragma unroll
    for (int a = 0; a < NA; ++a) {
      const int row = b*NA + a;
      const float gv = apts[row*3+0]*gw0 + apts[row*3+1]*gw1 + apts[row*3+2]*gw2;
      gm = fmaxf(gm, gg * (gv - gmean) * grstd + gb);
    }
#pragma unroll
    for (int a = 0; a < NA; ++a) {
      const int row = b*NA + a;
      const float resv = rg * (res_lin[(size_t)row*NC + c] - rmean) * rrstd + rb;
      feat_s[a][c]      = lf[(size_t)row*NC + c] + resv;
      feat_s[a][NC + c] = gm;
    }
    __syncthreads();

    // prob GEMM: wave m handles row b*4+m; 9 outputs via lane-split dot + butterfly
    const int m = t >> 6, lane = t & 63;
    for (int j = 0; j < 9; ++j) {
      float p = 0.f;
#pragma unroll
      for (int k2 = 0; k2 < 8; ++k2) {
        const int cc = lane + 64*k2;
        p = fmaf(feat_s[m][cc], prob_W[j*2*NC + cc], p);
      }
#pragma unroll
      for (int off = 1; off < 64; off <<= 1) p += __shfl_xor(p, off);
      if (lane == 0) prob_ln[(b*NA+m)*9 + j] = p;
    }
  }
  grid.sync();

  // ================= Phase 4 (block 0): prob-BN -> out =================
  if (blk == 0) {
    if (t < 9) {
      float s = 0.f, ss = 0.f;
      for (int i = 0; i < NROW; ++i) { const float v = prob_ln[i*9+t]; s += v; ss += v*v; }
      const float m  = s * (1.0f/NROW);
      const float va = ss * (1.0f/NROW) - m*m;
      pmn[t] = m; prs[t] = 1.0f / sqrtf(va + 1e-5f);
    }
    __syncthreads();
    for (int i = t; i < NROW*9; i += 256) {
      const int j = i % 9;
      out[i] = prob_gamma[j] * (prob_ln[i] - pmn[j]) * prs[j] + prob_beta[j];
    }
  }
}

extern "C" void kernel_launch(void* const* d_in, const int* in_sizes, int n_in,
                              void* d_out, int out_size, void* d_ws, size_t ws_size,
                              hipStream_t stream) {
  const float* a_points  = (const float*)d_in[0];
  const float* sa_x      = (const float*)d_in[1];
  const float* sa_xyz    = (const float*)d_in[2];
  // d_in[3] xyz_raw: unused by the reference
  const float* g_W       = (const float*)d_in[4];
  const float* g_gamma   = (const float*)d_in[5];
  const float* g_beta    = (const float*)d_in[6];
  const float* qkv_W     = (const float*)d_in[7];
  const float* pos_W     = (const float*)d_in[8];
  const float* pos_b     = (const float*)d_in[9];
  const float* pos_gamma = (const float*)d_in[10];
  const float* pos_beta  = (const float*)d_in[11];
  const float* res_W     = (const float*)d_in[12];
  const float* res_b     = (const float*)d_in[13];
  const float* res_gamma = (const float*)d_in[14];
  const float* res_beta  = (const float*)d_in[15];
  const float* prob_W    = (const float*)d_in[16];
  const float* prob_gamma= (const float*)d_in[17];
  const float* prob_beta = (const float*)d_in[18];
  float* ws  = (float*)d_ws;
  float* out = (float*)d_out;

  void* args[] = {
    (void*)&a_points, (void*)&sa_x, (void*)&sa_xyz,
    (void*)&g_W, (void*)&g_gamma, (void*)&g_beta,
    (void*)&qkv_W,
    (void*)&pos_W, (void*)&pos_b, (void*)&pos_gamma, (void*)&pos_beta,
    (void*)&res_W, (void*)&res_b, (void*)&res_gamma, (void*)&res_beta,
    (void*)&prob_W, (void*)&prob_gamma, (void*)&prob_beta,
    (void*)&ws, (void*)&out
  };
  hipLaunchCooperativeKernel((void*)fused_kernel, dim3(NROW), dim3(256), args, 0, stream);
}

// Round 4
// 70.838 us; speedup vs baseline: 2.4447x; 2.4447x over previous
//
#include <hip/hip_runtime.h>
#include <math.h>

#define NPTS 16384
#define NB   32
#define NA   4
#define NC   256
#define KNN  32
#define NROW 128   // NB*NA
#define CAP  2048  // candidate buffer (expected m ~ 33)

// ws layout (floats): lf 128*256 | qkv 128*768 | res_lin 128*256 | prob_lin 128*9
#define OFF_QKV     32768
#define OFF_RESLIN  131072
#define OFF_PROBLIN 163840

// ================= K1: knn (threshold select) + maxpool + row-qkv =================
__global__ __launch_bounds__(512) void knn_kernel(
    const float* __restrict__ a_points, const float* __restrict__ sa_xyz,
    const float* __restrict__ sa_x, const float* __restrict__ qkv_W,
    float* __restrict__ lf, float* __restrict__ qkv)
{
  const int blk = blockIdx.x;       // b*4 + a
  const int b   = blk >> 2;
  const int t   = threadIdx.x;

  __shared__ float s_T;
  __shared__ int   s_m;
  __shared__ uint2 s_cand[CAP];     // (dist_bits, idx) — 16 KB
  __shared__ int   s_top[KNN];
  __shared__ float s_lf2[2][NC];
  __shared__ float lf_s[NC];
  float* smin = (float*)s_cand;     // alias: 512 floats, consumed before collect

  const float ax = a_points[blk*3 + 0];
  const float ay = a_points[blk*3 + 1];
  const float az = a_points[blk*3 + 2];
  const float* __restrict__ xyz = sa_xyz + (size_t)b * NPTS * 3;

  // ---- distances: 32 per thread, registers only ----
  float d[32];
#pragma unroll
  for (int j = 0; j < 32; ++j) {
    const int n = t + 512*j;
    const float dx = xyz[n*3+0] - ax;
    const float dy = xyz[n*3+1] - ay;
    const float dz = xyz[n*3+2] - az;
    d[j] = dx*dx + dy*dy + dz*dz;
  }
  float mn = d[0];
#pragma unroll
  for (int j = 1; j < 32; ++j) mn = fminf(mn, d[j]);
  if (t == 0) s_m = 0;
  smin[t] = mn;
  __syncthreads();

  // ---- wave 0: binary search the 32nd-smallest of the 512 per-thread minima ----
  // (dist >= 0 -> float bits are monotone in value)
  if (t < 64) {
    unsigned v[8];
#pragma unroll
    for (int q = 0; q < 8; ++q) v[q] = __float_as_uint(smin[t + 64*q]);
    unsigned lo = 0u, hi = 0x7f7fffffu;
    while (lo < hi) {
      const unsigned mid = lo + ((hi - lo) >> 1);
      int cnt = 0;
#pragma unroll
      for (int q = 0; q < 8; ++q) cnt += (int)__popcll(__ballot(v[q] <= mid));
      if (cnt >= KNN) hi = mid; else lo = mid + 1;
    }
    if (t == 0) s_T = __uint_as_float(lo);
  }
  __syncthreads();
  const float T = s_T;   // guarantees count(d <= T) >= 32 and superset of true top-32

  // ---- collect candidates ----
#pragma unroll
  for (int j = 0; j < 32; ++j) {
    if (d[j] <= T) {
      const int pos = atomicAdd(&s_m, 1);
      if (pos < CAP) s_cand[pos] = make_uint2(__float_as_uint(d[j]), (unsigned)(t + 512*j));
    }
  }
  __syncthreads();
  const int m = (s_m < CAP) ? s_m : CAP;

  // ---- exact lex rank (dist, idx); ranks are a permutation 0..m-1 ----
  for (int c2 = t; c2 < m; c2 += 512) {
    const uint2 me = s_cand[c2];
    int rank = 0;
    for (int j = 0; j < m; ++j) {
      const uint2 o = s_cand[j];
      rank += (o.x < me.x) || (o.x == me.x && o.y < me.y);
    }
    if (rank < KNN) s_top[rank] = (int)me.y;
  }
  __syncthreads();

  // ---- gather + maxpool: c = t&255, half h = t>>8 covers 16 rows ----
  {
    const int c = t & 255, h = t >> 8;
    const float* __restrict__ xb = sa_x + (size_t)b * NPTS * NC;
    float acc = -3.0e38f;
    for (int r = h*16; r < h*16 + 16; ++r)
      acc = fmaxf(acc, xb[(size_t)s_top[r] * NC + c]);
    s_lf2[h][c] = acc;
  }
  __syncthreads();
  if (t < NC) {
    const float v = fmaxf(s_lf2[0][t], s_lf2[1][t]);
    lf_s[t] = v;
    lf[(size_t)blk * NC + t] = v;
  }
  __syncthreads();

  // ---- row-qkv GEMM: outputs o = t (all 512) and o = 512+t (t<256) ----
  {
    const float* __restrict__ w1 = qkv_W + (size_t)t * NC;
    float a1 = 0.f;
    for (int c = 0; c < NC; c += 4) {
      const float4 l4 = *(const float4*)&lf_s[c];
      const float4 w4 = *(const float4*)(w1 + c);
      a1 = fmaf(l4.x,w4.x,a1); a1 = fmaf(l4.y,w4.y,a1); a1 = fmaf(l4.z,w4.z,a1); a1 = fmaf(l4.w,w4.w,a1);
    }
    qkv[(size_t)blk*768 + t] = a1;
    if (t < 256) {
      const float* __restrict__ w2 = qkv_W + (size_t)(512 + t) * NC;
      float a2 = 0.f;
      for (int c = 0; c < NC; c += 4) {
        const float4 l4 = *(const float4*)&lf_s[c];
        const float4 w4 = *(const float4*)(w2 + c);
        a2 = fmaf(l4.x,w4.x,a2); a2 = fmaf(l4.y,w4.y,a2); a2 = fmaf(l4.z,w4.z,a2); a2 = fmaf(l4.w,w4.w,a2);
      }
      qkv[(size_t)blk*768 + 512 + t] = a2;
    }
  }
}

// ================= K2: pos-BN + attention + res GEMM (32 blocks) =================
__global__ __launch_bounds__(256) void attn_kernel(
    const float* __restrict__ a_points, const float* __restrict__ qkv,
    const float* __restrict__ pos_W, const float* __restrict__ pos_b,
    const float* __restrict__ pos_gamma, const float* __restrict__ pos_beta,
    const float* __restrict__ res_W, const float* __restrict__ res_b,
    float* __restrict__ res_lin)
{
  const int b = blockIdx.x;
  const int t = threadIdx.x;
  __shared__ float apts[NROW * 3];
  __shared__ float av_s[NA][NC];
  for (int i = t; i < NROW*3; i += 256) apts[i] = a_points[i];
  __syncthreads();

  const int c = t;
  const float pw0 = pos_W[c*3+0], pw1 = pos_W[c*3+1], pw2 = pos_W[c*3+2];
  const float pbb = pos_b[c];
  float psum = 0.f, pss = 0.f;
  float posv[NA];
#pragma unroll
  for (int a = 0; a < NA; ++a) posv[a] = 0.f;
  for (int b2 = 0; b2 < NB; ++b2) {
    float gx=0.f, gy=0.f, gz=0.f;
#pragma unroll
    for (int a = 0; a < NA; ++a) {
      gx += apts[(b2*NA+a)*3+0];
      gy += apts[(b2*NA+a)*3+1];
      gz += apts[(b2*NA+a)*3+2];
    }
    gx *= 0.25f; gy *= 0.25f; gz *= 0.25f;
#pragma unroll
    for (int a = 0; a < NA; ++a) {
      const float v = (apts[(b2*NA+a)*3+0]-gx)*pw0
                    + (apts[(b2*NA+a)*3+1]-gy)*pw1
                    + (apts[(b2*NA+a)*3+2]-gz)*pw2 + pbb;
      psum += v; pss += v*v;
      if (b2 == b) posv[a] = v;
    }
  }
  const float pmean = psum * (1.0f/NROW);
  const float pvar  = pss * (1.0f/NROW) - pmean*pmean;
  const float prstd = 1.0f / sqrtf(pvar + 1e-5f);
  const float pga = pos_gamma[c], pbe = pos_beta[c];

  float q[NA], k[NA], vv[NA];
#pragma unroll
  for (int a = 0; a < NA; ++a) {
    const int row = b*NA + a;
    const float p = pga * (posv[a] - pmean) * prstd + pbe;
    q[a]  = qkv[(size_t)row*768 +       c] + p;
    k[a]  = qkv[(size_t)row*768 + 256 + c] + p;
    vv[a] = qkv[(size_t)row*768 + 512 + c] + p;
  }
  // wave = head (c = head*64 + lane)
  float s[NA][NA];
#pragma unroll
  for (int m = 0; m < NA; ++m) {
#pragma unroll
    for (int n = 0; n < NA; ++n) {
      float p = q[m]*k[n];
#pragma unroll
      for (int off = 1; off < 64; off <<= 1) p += __shfl_xor(p, off);
      s[m][n] = p * 0.125f;   // 1/sqrt(64)
    }
  }
#pragma unroll
  for (int m = 0; m < NA; ++m) {
    const float mx = fmaxf(fmaxf(s[m][0], s[m][1]), fmaxf(s[m][2], s[m][3]));
    const float e0 = expf(s[m][0]-mx), e1 = expf(s[m][1]-mx);
    const float e2 = expf(s[m][2]-mx), e3 = expf(s[m][3]-mx);
    const float inv = 1.0f / (e0+e1+e2+e3);
    av_s[m][c] = (e0*vv[0] + e1*vv[1] + e2*vv[2] + e3*vv[3]) * inv;
  }
  __syncthreads();

  const float* __restrict__ wrow = res_W + (size_t)c * NC;
  float r0=0.f, r1=0.f, r2=0.f, r3=0.f;
  for (int cc = 0; cc < NC; cc += 4) {
    const float4 w4 = *(const float4*)(wrow + cc);
    const float4 v0 = *(const float4*)&av_s[0][cc];
    const float4 v1 = *(const float4*)&av_s[1][cc];
    const float4 v2 = *(const float4*)&av_s[2][cc];
    const float4 v3 = *(const float4*)&av_s[3][cc];
    r0 = fmaf(v0.x,w4.x,r0); r0 = fmaf(v0.y,w4.y,r0); r0 = fmaf(v0.z,w4.z,r0); r0 = fmaf(v0.w,w4.w,r0);
    r1 = fmaf(v1.x,w4.x,r1); r1 = fmaf(v1.y,w4.y,r1); r1 = fmaf(v1.z,w4.z,r1); r1 = fmaf(v1.w,w4.w,r1);
    r2 = fmaf(v2.x,w4.x,r2); r2 = fmaf(v2.y,w4.y,r2); r2 = fmaf(v2.z,w4.z,r2); r2 = fmaf(v2.w,w4.w,r2);
    r3 = fmaf(v3.x,w4.x,r3); r3 = fmaf(v3.y,w4.y,r3); r3 = fmaf(v3.z,w4.z,r3); r3 = fmaf(v3.w,w4.w,r3);
  }
  const float bias = res_b[c];
  res_lin[(size_t)(b*NA+0)*NC + c] = r0 + bias;
  res_lin[(size_t)(b*NA+1)*NC + c] = r1 + bias;
  res_lin[(size_t)(b*NA+2)*NC + c] = r2 + bias;
  res_lin[(size_t)(b*NA+3)*NC + c] = r3 + bias;
}

// ================= K3: res-BN + add, g-BN + max, prob GEMM (32 blocks) =================
__global__ __launch_bounds__(256) void final_kernel(
    const float* __restrict__ a_points,
    const float* __restrict__ lf, const float* __restrict__ res_lin,
    const float* __restrict__ res_gamma, const float* __restrict__ res_beta,
    const float* __restrict__ g_W, const float* __restrict__ g_gamma, const float* __restrict__ g_beta,
    const float* __restrict__ prob_W,
    float* __restrict__ prob_lin)
{
  const int b = blockIdx.x;
  const int t = threadIdx.x;
  __shared__ float apts[NROW * 3];
  __shared__ float feat_s[NA][2 * NC];
  for (int i = t; i < NROW*3; i += 256) apts[i] = a_points[i];
  __syncthreads();

  const int c = t;
  float rsum = 0.f, rss = 0.f;
  for (int row = 0; row < NROW; ++row) {
    const float v = res_lin[(size_t)row*NC + c];
    rsum += v; rss += v*v;
  }
  const float rmean = rsum * (1.0f/NROW);
  const float rvar  = rss * (1.0f/NROW) - rmean*rmean;
  const float rrstd = 1.0f / sqrtf(rvar + 1e-5f);
  const float rg = res_gamma[c], rb = res_beta[c];

  const float gw0 = g_W[c*3+0], gw1 = g_W[c*3+1], gw2 = g_W[c*3+2];
  float gsum = 0.f, gss = 0.f;
  for (int row = 0; row < NROW; ++row) {
    const float v = apts[row*3+0]*gw0 + apts[row*3+1]*gw1 + apts[row*3+2]*gw2;
    gsum += v; gss += v*v;
  }
  const float gmean = gsum * (1.0f/NROW);
  const float gvar  = gss * (1.0f/NROW) - gmean*gmean;
  const float grstd = 1.0f / sqrtf(gvar + 1e-5f);
  const float gg = g_gamma[c], gb = g_beta[c];

  float gm = -3.0e38f;
#pragma unroll
  for (int a = 0; a < NA; ++a) {
    const int row = b*NA + a;
    const float gv = apts[row*3+0]*gw0 + apts[row*3+1]*gw1 + apts[row*3+2]*gw2;
    gm = fmaxf(gm, gg * (gv - gmean) * grstd + gb);
  }
#pragma unroll
  for (int a = 0; a < NA; ++a) {
    const int row = b*NA + a;
    const float resv = rg * (res_lin[(size_t)row*NC + c] - rmean) * rrstd + rb;
    feat_s[a][c]      = lf[(size_t)row*NC + c] + resv;
    feat_s[a][NC + c] = gm;
  }
  __syncthreads();

  const int m = t >> 6, lane = t & 63;
  for (int j = 0; j < 9; ++j) {
    float p = 0.f;
#pragma unroll
    for (int k2 = 0; k2 < 8; ++k2) {
      const int cc = lane + 64*k2;
      p = fmaf(feat_s[m][cc], prob_W[j*2*NC + cc], p);
    }
#pragma unroll
    for (int off = 1; off < 64; off <<= 1) p += __shfl_xor(p, off);
    if (lane == 0) prob_lin[(b*NA+m)*9 + j] = p;
  }
}

// ================= K4: prob-BN -> out (1 block) =================
__global__ __launch_bounds__(256) void out_kernel(
    const float* __restrict__ prob_lin,
    const float* __restrict__ prob_gamma, const float* __restrict__ prob_beta,
    float* __restrict__ out)
{
  const int t = threadIdx.x;
  __shared__ float pmn[9], prs[9];
  if (t < 9) {
    float s = 0.f, ss = 0.f;
    for (int i = 0; i < NROW; ++i) { const float v = prob_lin[i*9+t]; s += v; ss += v*v; }
    const float m  = s * (1.0f/NROW);
    const float va = ss * (1.0f/NROW) - m*m;
    pmn[t] = m; prs[t] = 1.0f / sqrtf(va + 1e-5f);
  }
  __syncthreads();
  for (int i = t; i < NROW*9; i += 256) {
    const int j = i % 9;
    out[i] = prob_gamma[j] * (prob_lin[i] - pmn[j]) * prs[j] + prob_beta[j];
  }
}

extern "C" void kernel_launch(void* const* d_in, const int* in_sizes, int n_in,
                              void* d_out, int out_size, void* d_ws, size_t ws_size,
                              hipStream_t stream) {
  const float* a_points  = (const float*)d_in[0];
  const float* sa_x      = (const float*)d_in[1];
  const float* sa_xyz    = (const float*)d_in[2];
  // d_in[3] xyz_raw: unused by the reference
  const float* g_W       = (const float*)d_in[4];
  const float* g_gamma   = (const float*)d_in[5];
  const float* g_beta    = (const float*)d_in[6];
  const float* qkv_W     = (const float*)d_in[7];
  const float* pos_W     = (const float*)d_in[8];
  const float* pos_b     = (const float*)d_in[9];
  const float* pos_gamma = (const float*)d_in[10];
  const float* pos_beta  = (const float*)d_in[11];
  const float* res_W     = (const float*)d_in[12];
  const float* res_b     = (const float*)d_in[13];
  const float* res_gamma = (const float*)d_in[14];
  const float* res_beta  = (const float*)d_in[15];
  const float* prob_W    = (const float*)d_in[16];
  const float* prob_gamma= (const float*)d_in[17];
  const float* prob_beta = (const float*)d_in[18];
  float* ws  = (float*)d_ws;
  float* out = (float*)d_out;

  knn_kernel<<<NROW, 512, 0, stream>>>(a_points, sa_xyz, sa_x, qkv_W,
      ws, ws + OFF_QKV);
  attn_kernel<<<NB, 256, 0, stream>>>(a_points, ws + OFF_QKV,
      pos_W, pos_b, pos_gamma, pos_beta, res_W, res_b, ws + OFF_RESLIN);
  final_kernel<<<NB, 256, 0, stream>>>(a_points, ws, ws + OFF_RESLIN,
      res_gamma, res_beta, g_W, g_gamma, g_beta, prob_W, ws + OFF_PROBLIN);
  out_kernel<<<1, 256, 0, stream>>>(ws + OFF_PROBLIN, prob_gamma, prob_beta, out);
}

// Round 5
// 63.798 us; speedup vs baseline: 2.7145x; 1.1103x over previous
//
#include <hip/hip_runtime.h>
#include <math.h>

#define NPTS 16384
#define HALF 8192
#define NB   32
#define NA   4
#define NC   256
#define KNN  32
#define NROW 128   // NB*NA
#define CAP  1024

// ws layout (float offsets)
#define OFF_LF      0        // 128*256
#define OFF_QKV     32768    // 128*768
#define OFF_RESLIN  131072   // 128*256
#define OFF_POSLIN  163840   // 128*256
#define OFF_POSST   196608   // 512
#define OFF_GLIN    197120   // 128*256
#define OFF_GST     229888   // 512
#define OFF_PROBLIN 230400   // 1152
#define OFF_CAND    231552   // 256*32*2 (uint2) = 16384 floats
// total 247936 floats ~= 0.99 MB

// ========== K1: per-half knn: local exact top-32 (threshold + rank) ==========
__global__ __launch_bounds__(512) void knn_part_kernel(
    const float* __restrict__ a_points, const float* __restrict__ sa_xyz,
    uint2* __restrict__ cand)
{
  const int blk  = blockIdx.x;     // row*2 + half
  const int row  = blk >> 1;       // b*4 + a
  const int half = blk & 1;
  const int b    = row >> 2;
  const int t    = threadIdx.x;

  __shared__ float s_T;
  __shared__ int   s_m;
  __shared__ uint2 s_cand[CAP];    // 8 KB
  float* smin = (float*)s_cand;    // alias: 512 floats, consumed before collect

  const float ax = a_points[row*3 + 0];
  const float ay = a_points[row*3 + 1];
  const float az = a_points[row*3 + 2];
  const float* __restrict__ xyz = sa_xyz + (size_t)b * NPTS * 3 + (size_t)half * HALF * 3;

  float d[16];
#pragma unroll
  for (int j = 0; j < 16; ++j) {
    const int n = t + 512*j;
    const float dx = xyz[n*3+0] - ax;
    const float dy = xyz[n*3+1] - ay;
    const float dz = xyz[n*3+2] - az;
    d[j] = dx*dx + dy*dy + dz*dz;
  }
  float mn = d[0];
#pragma unroll
  for (int j = 1; j < 16; ++j) mn = fminf(mn, d[j]);
  if (t == 0) s_m = 0;
  smin[t] = mn;
  __syncthreads();

  // wave 0: binary search the 32nd-smallest of 512 per-thread minima (bits monotone for d>=0)
  if (t < 64) {
    unsigned v[8];
#pragma unroll
    for (int q = 0; q < 8; ++q) v[q] = __float_as_uint(smin[t + 64*q]);
    unsigned lo = 0u, hi = 0x7f7fffffu;
    while (lo < hi) {
      const unsigned mid = lo + ((hi - lo) >> 1);
      int cnt = 0;
#pragma unroll
      for (int q = 0; q < 8; ++q) cnt += (int)__popcll(__ballot(v[q] <= mid));
      if (cnt >= KNN) hi = mid; else lo = mid + 1;
    }
    if (t == 0) s_T = __uint_as_float(lo);
  }
  __syncthreads();
  const float T = s_T;   // count(d<=T) >= 32 and superset of local top-32

#pragma unroll
  for (int j = 0; j < 16; ++j) {
    if (d[j] <= T) {
      const int pos = atomicAdd(&s_m, 1);
      if (pos < CAP) s_cand[pos] = make_uint2(__float_as_uint(d[j]),
                                              (unsigned)(half*HALF + t + 512*j));
    }
  }
  __syncthreads();
  const int m = (s_m < CAP) ? s_m : CAP;

  // exact lex rank (dist, idx); write sorted top-32 straight to ws
  for (int c2 = t; c2 < m; c2 += 512) {
    const uint2 me = s_cand[c2];
    int rank = 0;
    for (int j = 0; j < m; ++j) {
      const uint2 o = s_cand[j];
      rank += (o.x < me.x) || (o.x == me.x && o.y < me.y);
    }
    if (rank < KNN) cand[(size_t)blk*KNN + rank] = me;
  }
}

// ========== K2: merge 64->32, gather + maxpool ==========
__global__ __launch_bounds__(256) void gather_kernel(
    const uint2* __restrict__ cand, const float* __restrict__ sa_x,
    float* __restrict__ lf)
{
  const int row = blockIdx.x;      // b*4 + a
  const int b   = row >> 2;
  const int t   = threadIdx.x;
  __shared__ uint2 s64[64];
  __shared__ int   s_top[KNN];
  if (t < 64) s64[t] = cand[(size_t)row*64 + t];
  __syncthreads();
  if (t < 64) {
    const uint2 me = s64[t];
    int rank = 0;
#pragma unroll
    for (int j = 0; j < 64; ++j) {
      const uint2 o = s64[j];
      rank += (o.x < me.x) || (o.x == me.x && o.y < me.y);
    }
    if (rank < KNN) s_top[rank] = (int)me.y;
  }
  __syncthreads();

  const float* __restrict__ xb = sa_x + (size_t)b * NPTS * NC;
  float acc = -3.0e38f;
#pragma unroll
  for (int r = 0; r < KNN; ++r)
    acc = fmaxf(acc, xb[(size_t)s_top[r] * NC + t]);
  lf[(size_t)row * NC + t] = acc;
}

// ========== K3: qkv GEMM tiles + pos_lin/stats + g_lin/stats ==========
__global__ __launch_bounds__(256) void lin1_kernel(
    const float* __restrict__ lf, const float* __restrict__ qkv_W,
    const float* __restrict__ a_points,
    const float* __restrict__ pos_W, const float* __restrict__ pos_b,
    const float* __restrict__ g_W,
    float* __restrict__ qkv, float* __restrict__ pos_lin, float* __restrict__ pos_stats,
    float* __restrict__ g_lin, float* __restrict__ g_stats)
{
  const int blk = blockIdx.x;
  if (blk < 96) {
    // 8 rowtiles(16) x 12 otiles(64); thread = (ot 0..63, rt 0..3), 4 rows each
    const int r0 = (blk / 12) * 16;
    const int o0 = (blk % 12) * 64;
    const int ot = threadIdx.x & 63;
    const int rt = threadIdx.x >> 6;
    const int o  = o0 + ot;
    const float* __restrict__ wrow = qkv_W + (size_t)o * NC;
    const float* __restrict__ l0p  = lf + (size_t)(r0 + rt*4) * NC;
    float acc0 = 0.f, acc1 = 0.f, acc2 = 0.f, acc3 = 0.f;
    for (int c = 0; c < NC; c += 4) {
      const float4 w4 = *(const float4*)(wrow + c);
      const float4 l0 = *(const float4*)(l0p + c);
      const float4 l1 = *(const float4*)(l0p + NC + c);
      const float4 l2 = *(const float4*)(l0p + 2*NC + c);
      const float4 l3 = *(const float4*)(l0p + 3*NC + c);
      acc0 = fmaf(l0.x,w4.x,acc0); acc0 = fmaf(l0.y,w4.y,acc0); acc0 = fmaf(l0.z,w4.z,acc0); acc0 = fmaf(l0.w,w4.w,acc0);
      acc1 = fmaf(l1.x,w4.x,acc1); acc1 = fmaf(l1.y,w4.y,acc1); acc1 = fmaf(l1.z,w4.z,acc1); acc1 = fmaf(l1.w,w4.w,acc1);
      acc2 = fmaf(l2.x,w4.x,acc2); acc2 = fmaf(l2.y,w4.y,acc2); acc2 = fmaf(l2.z,w4.z,acc2); acc2 = fmaf(l2.w,w4.w,acc2);
      acc3 = fmaf(l3.x,w4.x,acc3); acc3 = fmaf(l3.y,w4.y,acc3); acc3 = fmaf(l3.z,w4.z,acc3); acc3 = fmaf(l3.w,w4.w,acc3);
    }
    const int r = r0 + rt*4;
    qkv[(size_t)(r+0)*768 + o] = acc0;
    qkv[(size_t)(r+1)*768 + o] = acc1;
    qkv[(size_t)(r+2)*768 + o] = acc2;
    qkv[(size_t)(r+3)*768 + o] = acc3;
  } else if (blk == 96) {
    __shared__ float apts[NROW*3];
    for (int i = threadIdx.x; i < NROW*3; i += 256) apts[i] = a_points[i];
    __syncthreads();
    const int c = threadIdx.x;
    const float w0 = pos_W[c*3+0], w1 = pos_W[c*3+1], w2 = pos_W[c*3+2];
    const float bb = pos_b[c];
    float sum = 0.f, sumsq = 0.f;
    for (int b = 0; b < NB; ++b) {
      float gx=0.f, gy=0.f, gz=0.f;
#pragma unroll
      for (int a = 0; a < NA; ++a) {
        gx += apts[(b*NA+a)*3+0];
        gy += apts[(b*NA+a)*3+1];
        gz += apts[(b*NA+a)*3+2];
      }
      gx *= 0.25f; gy *= 0.25f; gz *= 0.25f;
#pragma unroll
      for (int a = 0; a < NA; ++a) {
        const float v = (apts[(b*NA+a)*3+0]-gx)*w0
                      + (apts[(b*NA+a)*3+1]-gy)*w1
                      + (apts[(b*NA+a)*3+2]-gz)*w2 + bb;
        pos_lin[(b*NA+a)*NC + c] = v;
        sum += v; sumsq += v*v;
      }
    }
    pos_stats[c] = sum; pos_stats[NC + c] = sumsq;
  } else {
    __shared__ float apts[NROW*3];
    for (int i = threadIdx.x; i < NROW*3; i += 256) apts[i] = a_points[i];
    __syncthreads();
    const int c = threadIdx.x;
    const float w0 = g_W[c*3+0], w1 = g_W[c*3+1], w2 = g_W[c*3+2];
    float sum = 0.f, sumsq = 0.f;
    for (int r = 0; r < NROW; ++r) {
      const float v = apts[r*3+0]*w0 + apts[r*3+1]*w1 + apts[r*3+2]*w2;
      g_lin[r*NC + c] = v;
      sum += v; sumsq += v*v;
    }
    g_stats[c] = sum; g_stats[NC + c] = sumsq;
  }
}

// ========== K4: pos-BN apply + attention + res GEMM ==========
__global__ __launch_bounds__(256) void attn_kernel(
    const float* __restrict__ qkv, const float* __restrict__ pos_lin,
    const float* __restrict__ pos_stats,
    const float* __restrict__ pos_gamma, const float* __restrict__ pos_beta,
    const float* __restrict__ res_W, const float* __restrict__ res_b,
    float* __restrict__ res_lin)
{
  const int b = blockIdx.x;
  const int t = threadIdx.x;
  __shared__ float av_s[NA][NC];
  const int c = t;
  const float pmean = pos_stats[c] * (1.0f/NROW);
  const float pvar  = pos_stats[NC + c] * (1.0f/NROW) - pmean*pmean;
  const float prstd = 1.0f / sqrtf(pvar + 1e-5f);
  const float pga = pos_gamma[c], pbe = pos_beta[c];

  float q[NA], k[NA], vv[NA];
#pragma unroll
  for (int a = 0; a < NA; ++a) {
    const int row = b*NA + a;
    const float p = pga * (pos_lin[(size_t)row*NC + c] - pmean) * prstd + pbe;
    q[a]  = qkv[(size_t)row*768 +       c] + p;
    k[a]  = qkv[(size_t)row*768 + 256 + c] + p;
    vv[a] = qkv[(size_t)row*768 + 512 + c] + p;
  }
  float s[NA][NA];
#pragma unroll
  for (int m = 0; m < NA; ++m) {
#pragma unroll
    for (int n = 0; n < NA; ++n) {
      float p = q[m]*k[n];
#pragma unroll
      for (int off = 1; off < 64; off <<= 1) p += __shfl_xor(p, off);
      s[m][n] = p * 0.125f;   // 1/sqrt(64)
    }
  }
#pragma unroll
  for (int m = 0; m < NA; ++m) {
    const float mx = fmaxf(fmaxf(s[m][0], s[m][1]), fmaxf(s[m][2], s[m][3]));
    const float e0 = expf(s[m][0]-mx), e1 = expf(s[m][1]-mx);
    const float e2 = expf(s[m][2]-mx), e3 = expf(s[m][3]-mx);
    const float inv = 1.0f / (e0+e1+e2+e3);
    av_s[m][c] = (e0*vv[0] + e1*vv[1] + e2*vv[2] + e3*vv[3]) * inv;
  }
  __syncthreads();

  const float* __restrict__ wrow = res_W + (size_t)c * NC;
  float r0=0.f, r1=0.f, r2=0.f, r3=0.f;
  for (int cc = 0; cc < NC; cc += 4) {
    const float4 w4 = *(const float4*)(wrow + cc);
    const float4 v0 = *(const float4*)&av_s[0][cc];
    const float4 v1 = *(const float4*)&av_s[1][cc];
    const float4 v2 = *(const float4*)&av_s[2][cc];
    const float4 v3 = *(const float4*)&av_s[3][cc];
    r0 = fmaf(v0.x,w4.x,r0); r0 = fmaf(v0.y,w4.y,r0); r0 = fmaf(v0.z,w4.z,r0); r0 = fmaf(v0.w,w4.w,r0);
    r1 = fmaf(v1.x,w4.x,r1); r1 = fmaf(v1.y,w4.y,r1); r1 = fmaf(v1.z,w4.z,r1); r1 = fmaf(v1.w,w4.w,r1);
    r2 = fmaf(v2.x,w4.x,r2); r2 = fmaf(v2.y,w4.y,r2); r2 = fmaf(v2.z,w4.z,r2); r2 = fmaf(v2.w,w4.w,r2);
    r3 = fmaf(v3.x,w4.x,r3); r3 = fmaf(v3.y,w4.y,r3); r3 = fmaf(v3.z,w4.z,r3); r3 = fmaf(v3.w,w4.w,r3);
  }
  const float bias = res_b[c];
  res_lin[(size_t)(b*NA+0)*NC + c] = r0 + bias;
  res_lin[(size_t)(b*NA+1)*NC + c] = r1 + bias;
  res_lin[(size_t)(b*NA+2)*NC + c] = r2 + bias;
  res_lin[(size_t)(b*NA+3)*NC + c] = r3 + bias;
}

// ========== K5: res-BN + add, g-BN + max, prob GEMM ==========
__global__ __launch_bounds__(256) void final_kernel(
    const float* __restrict__ lf, const float* __restrict__ res_lin,
    const float* __restrict__ res_gamma, const float* __restrict__ res_beta,
    const float* __restrict__ g_lin, const float* __restrict__ g_stats,
    const float* __restrict__ g_gamma, const float* __restrict__ g_beta,
    const float* __restrict__ prob_W,
    float* __restrict__ prob_lin)
{
  const int b = blockIdx.x;
  const int t = threadIdx.x;
  __shared__ float feat_s[NA][2 * NC];
  const int c = t;
  float rsum = 0.f, rss = 0.f;
  for (int row = 0; row < NROW; ++row) {
    const float v = res_lin[(size_t)row*NC + c];
    rsum += v; rss += v*v;
  }
  const float rmean = rsum * (1.0f/NROW);
  const float rvar  = rss * (1.0f/NROW) - rmean*rmean;
  const float rrstd = 1.0f / sqrtf(rvar + 1e-5f);
  const float rg = res_gamma[c], rb = res_beta[c];

  const float gmean = g_stats[c] * (1.0f/NROW);
  const float gvar  = g_stats[NC+c] * (1.0f/NROW) - gmean*gmean;
  const float grstd = 1.0f / sqrtf(gvar + 1e-5f);
  const float gg = g_gamma[c], gb = g_beta[c];

  float gm = -3.0e38f;
#pragma unroll
  for (int a = 0; a < NA; ++a) {
    const int row = b*NA + a;
    gm = fmaxf(gm, gg * (g_lin[(size_t)row*NC + c] - gmean) * grstd + gb);
  }
#pragma unroll
  for (int a = 0; a < NA; ++a) {
    const int row = b*NA + a;
    const float resv = rg * (res_lin[(size_t)row*NC + c] - rmean) * rrstd + rb;
    feat_s[a][c]      = lf[(size_t)row*NC + c] + resv;
    feat_s[a][NC + c] = gm;
  }
  __syncthreads();

  const int m = t >> 6, lane = t & 63;
  for (int j = 0; j < 9; ++j) {
    float p = 0.f;
#pragma unroll
    for (int k2 = 0; k2 < 8; ++k2) {
      const int cc = lane + 64*k2;
      p = fmaf(feat_s[m][cc], prob_W[j*2*NC + cc], p);
    }
#pragma unroll
    for (int off = 1; off < 64; off <<= 1) p += __shfl_xor(p, off);
    if (lane == 0) prob_lin[(b*NA+m)*9 + j] = p;
  }
}

// ========== K6: prob-BN -> out ==========
__global__ __launch_bounds__(256) void out_kernel(
    const float* __restrict__ prob_lin,
    const float* __restrict__ prob_gamma, const float* __restrict__ prob_beta,
    float* __restrict__ out)
{
  const int t = threadIdx.x;
  __shared__ float pmn[9], prs[9];
  if (t < 9) {
    float s = 0.f, ss = 0.f;
    for (int i = 0; i < NROW; ++i) { const float v = prob_lin[i*9+t]; s += v; ss += v*v; }
    const float m  = s * (1.0f/NROW);
    const float va = ss * (1.0f/NROW) - m*m;
    pmn[t] = m; prs[t] = 1.0f / sqrtf(va + 1e-5f);
  }
  __syncthreads();
  for (int i = t; i < NROW*9; i += 256) {
    const int j = i % 9;
    out[i] = prob_gamma[j] * (prob_lin[i] - pmn[j]) * prs[j] + prob_beta[j];
  }
}

extern "C" void kernel_launch(void* const* d_in, const int* in_sizes, int n_in,
                              void* d_out, int out_size, void* d_ws, size_t ws_size,
                              hipStream_t stream) {
  const float* a_points  = (const float*)d_in[0];
  const float* sa_x      = (const float*)d_in[1];
  const float* sa_xyz    = (const float*)d_in[2];
  // d_in[3] xyz_raw: unused by the reference
  const float* g_W       = (const float*)d_in[4];
  const float* g_gamma   = (const float*)d_in[5];
  const float* g_beta    = (const float*)d_in[6];
  const float* qkv_W     = (const float*)d_in[7];
  const float* pos_W     = (const float*)d_in[8];
  const float* pos_b     = (const float*)d_in[9];
  const float* pos_gamma = (const float*)d_in[10];
  const float* pos_beta  = (const float*)d_in[11];
  const float* res_W     = (const float*)d_in[12];
  const float* res_b     = (const float*)d_in[13];
  const float* res_gamma = (const float*)d_in[14];
  const float* res_beta  = (const float*)d_in[15];
  const float* prob_W    = (const float*)d_in[16];
  const float* prob_gamma= (const float*)d_in[17];
  const float* prob_beta = (const float*)d_in[18];
  float* ws  = (float*)d_ws;
  float* out = (float*)d_out;

  knn_part_kernel<<<256, 512, 0, stream>>>(a_points, sa_xyz, (uint2*)(ws + OFF_CAND));
  gather_kernel<<<NROW, 256, 0, stream>>>((const uint2*)(ws + OFF_CAND), sa_x, ws + OFF_LF);
  lin1_kernel<<<98, 256, 0, stream>>>(ws + OFF_LF, qkv_W, a_points, pos_W, pos_b, g_W,
      ws + OFF_QKV, ws + OFF_POSLIN, ws + OFF_POSST, ws + OFF_GLIN, ws + OFF_GST);
  attn_kernel<<<NB, 256, 0, stream>>>(ws + OFF_QKV, ws + OFF_POSLIN, ws + OFF_POSST,
      pos_gamma, pos_beta, res_W, res_b, ws + OFF_RESLIN);
  final_kernel<<<NB, 256, 0, stream>>>(ws + OFF_LF, ws + OFF_RESLIN,
      res_gamma, res_beta, ws + OFF_GLIN, ws + OFF_GST, g_gamma, g_beta, prob_W,
      ws + OFF_PROBLIN);
  out_kernel<<<1, 256, 0, stream>>>(ws + OFF_PROBLIN, prob_gamma, prob_beta, out);
}